// Round 6
// baseline (219.938 us; speedup 1.0000x reference)
//
#include <hip/hip_runtime.h>
#include <hip/hip_bf16.h>
#include <stdint.h>
#include <stddef.h>

typedef __bf16 bf16_t;
typedef __bf16 bf16x8 __attribute__((ext_vector_type(8)));
typedef float floatx4 __attribute__((ext_vector_type(4)));

#define DIM 512
#define SEQ 4096
#define BATCH 8

static __device__ __forceinline__ floatx4 mfma_bf16(bf16x8 a, bf16x8 b, floatx4 c) {
  return __builtin_amdgcn_mfma_f32_16x16x32_bf16(a, b, c, 0, 0, 0);
}

typedef __attribute__((address_space(1))) const void* gas_ptr;
typedef __attribute__((address_space(3))) void* las_ptr;
static __device__ __forceinline__ void gll16(const void* g, void* l) {
  __builtin_amdgcn_global_load_lds((gas_ptr)g, (las_ptr)l, 16, 0, 0);
}

// ---------------- K0: fp32 -> bf16 converter (w_qkv and x) ----------------
__global__ __launch_bounds__(256) void k_cvt(const float* __restrict__ w, bf16_t* __restrict__ wb) {
  int i = (blockIdx.x * 256 + threadIdx.x) * 8;
  float4 a = *(const float4*)&w[i];
  float4 b = *(const float4*)&w[i + 4];
  bf16x8 o;
  o[0] = (bf16_t)a.x; o[1] = (bf16_t)a.y; o[2] = (bf16_t)a.z; o[3] = (bf16_t)a.w;
  o[4] = (bf16_t)b.x; o[5] = (bf16_t)b.y; o[6] = (bf16_t)b.z; o[7] = (bf16_t)b.w;
  *(bf16x8*)&wb[i] = o;
}

// ---------------- K1: qkv GEMM, 256x256 tile, 8 waves, BK=64 ----------------
// LDS[row][u16] = G[row][u16 ^ (row&7)] (16B units); read back with same XOR. 0-conflict (r5 verified).
__global__ __launch_bounds__(512, 2) void k_qkv(const bf16_t* __restrict__ Xb,
                                                const bf16_t* __restrict__ Wb,
                                                bf16_t* __restrict__ qs,
                                                bf16_t* __restrict__ ek,
                                                bf16_t* __restrict__ vb,
                                                float* __restrict__ S) {
  __shared__ __align__(16) bf16_t As[256 * 64];  // 32 KB
  __shared__ __align__(16) bf16_t Bs[256 * 64];  // 32 KB
  const int tid = threadIdx.x;
  const int lane = tid & 63;
  const int w = tid >> 6;              // 0..7
  const int wr = w >> 2, wc = w & 3;   // 2 x 4 wave grid; wave tile 128 x 64
  const int l15 = lane & 15, l4 = lane >> 4;
  const int m0 = blockIdx.x * 256;
  const int n0 = blockIdx.y * 256;

  const int srow = tid >> 3;                       // 0..63
  const int sunit = (tid & 7) ^ (srow & 7);        // pre-swizzled source unit
  const bf16_t* gA = Xb + (size_t)(m0 + srow) * DIM + (sunit << 3);
  const bf16_t* gB = Wb + (size_t)(n0 + srow) * DIM + (sunit << 3);
  bf16_t* lA = As + tid * 8;
  bf16_t* lB = Bs + tid * 8;

  floatx4 acc[8][4];
#pragma unroll
  for (int i = 0; i < 8; ++i)
#pragma unroll
    for (int j = 0; j < 4; ++j) acc[i][j] = (floatx4){0.f, 0.f, 0.f, 0.f};

  for (int kt = 0; kt < DIM; kt += 64) {
#pragma unroll
    for (int i = 0; i < 4; ++i) {
      gll16(gA + (size_t)i * 64 * DIM, lA + i * 64 * 64);
      gll16(gB + (size_t)i * 64 * DIM, lB + i * 64 * 64);
    }
    gA += 64; gB += 64;
    __syncthreads();
#pragma unroll
    for (int kk = 0; kk < 2; ++kk) {
      bf16x8 af[8], bfr[4];
#pragma unroll
      for (int f = 0; f < 8; ++f) {
        int ar = wr * 128 + f * 16 + l15;
        int ua = (kk * 4 + l4) ^ (ar & 7);
        af[f] = *(const bf16x8*)(As + ar * 64 + ua * 8);
      }
#pragma unroll
      for (int f = 0; f < 4; ++f) {
        int br = wc * 64 + f * 16 + l15;
        int ub = (kk * 4 + l4) ^ (br & 7);
        bfr[f] = *(const bf16x8*)(Bs + br * 64 + ub * 8);
      }
#pragma unroll
      for (int i = 0; i < 8; ++i)
#pragma unroll
        for (int j = 0; j < 4; ++j)
          acc[i][j] = mfma_bf16(af[i], bfr[j], acc[i][j]);
    }
    __syncthreads();
  }

  const int colbase = n0 + wc * 64;
  if (n0 < 512) {
    // q: softmax over the wave's 64 cols (one head), * 1/8
#pragma unroll
    for (int fm = 0; fm < 8; ++fm) {
#pragma unroll
      for (int r = 0; r < 4; ++r) {
        float v0 = acc[fm][0][r], v1 = acc[fm][1][r], v2 = acc[fm][2][r], v3 = acc[fm][3][r];
        float mx = fmaxf(fmaxf(v0, v1), fmaxf(v2, v3));
        mx = fmaxf(mx, __shfl_xor(mx, 1));
        mx = fmaxf(mx, __shfl_xor(mx, 2));
        mx = fmaxf(mx, __shfl_xor(mx, 4));
        mx = fmaxf(mx, __shfl_xor(mx, 8));
        float e0 = __expf(v0 - mx), e1 = __expf(v1 - mx), e2 = __expf(v2 - mx), e3 = __expf(v3 - mx);
        float s = e0 + e1 + e2 + e3;
        s += __shfl_xor(s, 1); s += __shfl_xor(s, 2); s += __shfl_xor(s, 4); s += __shfl_xor(s, 8);
        float inv = 0.125f / s;
        int m = m0 + wr * 128 + fm * 16 + l4 * 4 + r;
        bf16_t* rowp = qs + (size_t)m * DIM + colbase;
        rowp[l15]      = (bf16_t)(e0 * inv);
        rowp[16 + l15] = (bf16_t)(e1 * inv);
        rowp[32 + l15] = (bf16_t)(e2 * inv);
        rowp[48 + l15] = (bf16_t)(e3 * inv);
      }
    }
  } else if (n0 < 1024) {
    const int cb = colbase - 512;
    float c0 = 0.f, c1 = 0.f, c2 = 0.f, c3 = 0.f;
#pragma unroll
    for (int fm = 0; fm < 8; ++fm) {
#pragma unroll
      for (int r = 0; r < 4; ++r) {
        int m = m0 + wr * 128 + fm * 16 + l4 * 4 + r;
        bf16_t* rowp = ek + (size_t)m * DIM + cb;
        float e0 = __expf(acc[fm][0][r]);
        float e1 = __expf(acc[fm][1][r]);
        float e2 = __expf(acc[fm][2][r]);
        float e3 = __expf(acc[fm][3][r]);
        rowp[l15]      = (bf16_t)e0;
        rowp[16 + l15] = (bf16_t)e1;
        rowp[32 + l15] = (bf16_t)e2;
        rowp[48 + l15] = (bf16_t)e3;
        c0 += e0; c1 += e1; c2 += e2; c3 += e3;
      }
    }
    c0 += __shfl_xor(c0, 16); c0 += __shfl_xor(c0, 32);
    c1 += __shfl_xor(c1, 16); c1 += __shfl_xor(c1, 32);
    c2 += __shfl_xor(c2, 16); c2 += __shfl_xor(c2, 32);
    c3 += __shfl_xor(c3, 16); c3 += __shfl_xor(c3, 32);
    if (lane < 16) {
      int b = m0 >> 12;
      atomicAdd(&S[b * 512 + cb + lane],      c0);
      atomicAdd(&S[b * 512 + cb + 16 + lane], c1);
      atomicAdd(&S[b * 512 + cb + 32 + lane], c2);
      atomicAdd(&S[b * 512 + cb + 48 + lane], c3);
    }
  } else {
    const int cb = colbase - 1024;
#pragma unroll
    for (int fm = 0; fm < 8; ++fm) {
#pragma unroll
      for (int r = 0; r < 4; ++r) {
        int m = m0 + wr * 128 + fm * 16 + l4 * 4 + r;
        bf16_t* rowp = vb + (size_t)m * DIM + cb;
        rowp[l15]      = (bf16_t)acc[fm][0][r];
        rowp[16 + l15] = (bf16_t)acc[fm][1][r];
        rowp[32 + l15] = (bf16_t)acc[fm][2][r];
        rowp[48 + l15] = (bf16_t)acc[fm][3][r];
      }
    }
  }
}

// ---------------- K2: ctxpart[b,h,chunk] = ek_chunk^T @ v_chunk (64x64) ----------------
#define TP 136
__global__ __launch_bounds__(256) void k_ctx(const bf16_t* __restrict__ ek,
                                             const bf16_t* __restrict__ vb,
                                             float* __restrict__ ctxpart) {
  __shared__ __align__(16) bf16_t ekT[64 * TP];
  __shared__ __align__(16) bf16_t vT[64 * TP];
  __shared__ float red[4096];
  const int tid = threadIdx.x;
  const int lane = tid & 63, wid = tid >> 6;
  const int l15 = lane & 15, l4 = lane >> 4;
  const int bh = blockIdx.x, chunk = blockIdx.y;
  const int b = bh >> 3, h = bh & 7;
  const int base = b * SEQ + chunk * 512;

  floatx4 acc[4][4];
#pragma unroll
  for (int i = 0; i < 4; ++i)
#pragma unroll
    for (int j = 0; j < 4; ++j) acc[i][j] = (floatx4){0.f, 0.f, 0.f, 0.f};

  for (int nt = 0; nt < 4; ++nt) {
    const int n0 = base + nt * 128;
#pragma unroll
    for (int i = 0; i < 4; ++i) {
      int q = tid + i * 256;
      int n = q & 127;
      int c8 = (q >> 7) << 3;
      bf16x8 vk = *(const bf16x8*)&ek[(size_t)(n0 + n) * DIM + h * 64 + c8];
      bf16x8 vv = *(const bf16x8*)&vb[(size_t)(n0 + n) * DIM + h * 64 + c8];
#pragma unroll
      for (int j = 0; j < 8; ++j) {
        ekT[(c8 + j) * TP + n] = vk[j];
        vT [(c8 + j) * TP + n] = vv[j];
      }
    }
    __syncthreads();
    const int nb = wid * 32;
    bf16x8 af[4], bfr[4];
#pragma unroll
    for (int f = 0; f < 4; ++f) {
      af[f]  = *(const bf16x8*)&ekT[(f * 16 + l15) * TP + nb + l4 * 8];
      bfr[f] = *(const bf16x8*)&vT [(f * 16 + l15) * TP + nb + l4 * 8];
    }
#pragma unroll
    for (int i = 0; i < 4; ++i)
#pragma unroll
      for (int j = 0; j < 4; ++j)
        acc[i][j] = mfma_bf16(af[i], bfr[j], acc[i][j]);
    __syncthreads();
  }

  for (int w = 0; w < 4; ++w) {
    if (wid == w) {
#pragma unroll
      for (int fm = 0; fm < 4; ++fm)
#pragma unroll
        for (int fn = 0; fn < 4; ++fn)
#pragma unroll
          for (int r = 0; r < 4; ++r) {
            int d = fm * 16 + l4 * 4 + r;
            int e = fn * 16 + l15;
            if (w == 0) red[d * 64 + e] = acc[fm][fn][r];
            else        red[d * 64 + e] += acc[fm][fn][r];
          }
    }
    __syncthreads();
  }
  float* dst = ctxpart + ((size_t)bh * 8 + chunk) * 4096;
#pragma unroll
  for (int i = 0; i < 4; ++i) {
    int q = tid + i * 256;
    *(float4*)&dst[q * 4] = *(const float4*)&red[q * 4];
  }
}

// ---------------- K3: (merged) reduce partials, /S, then Mt[b][dcol][h*64+d] ----------------
__global__ __launch_bounds__(256) void k_mt(const float* __restrict__ ctxpart,
                                            const float* __restrict__ S,
                                            const float* __restrict__ w_out,
                                            bf16_t* __restrict__ Mt) {
  __shared__ float cs[4096];
  const int tid = threadIdx.x;
  const int bh = blockIdx.x;
  const int b = bh >> 3, h = bh & 7;
#pragma unroll
  for (int i = 0; i < 16; ++i) {
    int idx = tid + i * 256;
    float s = 0.f;
#pragma unroll
    for (int p = 0; p < 8; ++p) s += ctxpart[((size_t)bh * 8 + p) * 4096 + idx];
    cs[idx] = s / S[b * 512 + h * 64 + (idx >> 6)];
  }
  __syncthreads();
  for (int half = 0; half < 2; ++half) {
    const int dcol = half * 256 + tid;
    float a[64];
#pragma unroll
    for (int d = 0; d < 64; ++d) a[d] = 0.f;
    for (int e = 0; e < 64; ++e) {
      float we = w_out[(size_t)dcol * 512 + h * 64 + e];
#pragma unroll
      for (int d = 0; d < 64; ++d) a[d] += cs[d * 64 + e] * we;
    }
    bf16_t* dst = Mt + ((size_t)b * 512 + dcol) * 512 + h * 64;
#pragma unroll
    for (int g = 0; g < 8; ++g) {
      bf16x8 o;
#pragma unroll
      for (int j = 0; j < 8; ++j) o[j] = (bf16_t)a[g * 8 + j];
      *(bf16x8*)&dst[g * 8] = o;
    }
  }
}

// ---------------- K4: out2b[b] = qs[b] @ Mt[b], 256x256 tile, 8 waves ----------------
__global__ __launch_bounds__(512, 2) void k_out(const bf16_t* __restrict__ qs,
                                                const bf16_t* __restrict__ Mt,
                                                bf16_t* __restrict__ out2b) {
  __shared__ __align__(16) bf16_t As[256 * 64];
  __shared__ __align__(16) bf16_t Bs[256 * 64];
  const int tid = threadIdx.x;
  const int lane = tid & 63;
  const int w = tid >> 6;
  const int wr = w >> 2, wc = w & 3;
  const int l15 = lane & 15, l4 = lane >> 4;
  const int m0 = blockIdx.x * 256;
  const int n0 = blockIdx.y * 256;
  const bf16_t* Bp = Mt + (size_t)(blockIdx.x >> 4) * 512 * 512;  // batch = m0>>12

  const int srow = tid >> 3;
  const int sunit = (tid & 7) ^ (srow & 7);
  const bf16_t* gA = qs + (size_t)(m0 + srow) * 512 + (sunit << 3);
  const bf16_t* gB = Bp + (size_t)(n0 + srow) * 512 + (sunit << 3);
  bf16_t* lA = As + tid * 8;
  bf16_t* lB = Bs + tid * 8;

  floatx4 acc[8][4];
#pragma unroll
  for (int i = 0; i < 8; ++i)
#pragma unroll
    for (int j = 0; j < 4; ++j) acc[i][j] = (floatx4){0.f, 0.f, 0.f, 0.f};

  for (int kt = 0; kt < 512; kt += 64) {
#pragma unroll
    for (int i = 0; i < 4; ++i) {
      gll16(gA + (size_t)i * 64 * 512, lA + i * 64 * 64);
      gll16(gB + (size_t)i * 64 * 512, lB + i * 64 * 64);
    }
    gA += 64; gB += 64;
    __syncthreads();
#pragma unroll
    for (int kk = 0; kk < 2; ++kk) {
      bf16x8 af[8], bfr[4];
#pragma unroll
      for (int f = 0; f < 8; ++f) {
        int ar = wr * 128 + f * 16 + l15;
        int ua = (kk * 4 + l4) ^ (ar & 7);
        af[f] = *(const bf16x8*)(As + ar * 64 + ua * 8);
      }
#pragma unroll
      for (int f = 0; f < 4; ++f) {
        int br = wc * 64 + f * 16 + l15;
        int ub = (kk * 4 + l4) ^ (br & 7);
        bfr[f] = *(const bf16x8*)(Bs + br * 64 + ub * 8);
      }
#pragma unroll
      for (int i = 0; i < 8; ++i)
#pragma unroll
        for (int j = 0; j < 4; ++j)
          acc[i][j] = mfma_bf16(af[i], bfr[j], acc[i][j]);
    }
    __syncthreads();
  }
#pragma unroll
  for (int fm = 0; fm < 8; ++fm) {
#pragma unroll
    for (int r = 0; r < 4; ++r) {
      int m = m0 + wr * 128 + fm * 16 + l4 * 4 + r;
      bf16_t* rowp = out2b + (size_t)m * 512 + n0 + wc * 64;
      rowp[l15]      = (bf16_t)acc[fm][0][r];
      rowp[16 + l15] = (bf16_t)acc[fm][1][r];
      rowp[32 + l15] = (bf16_t)acc[fm][2][r];
      rowp[48 + l15] = (bf16_t)acc[fm][3][r];
    }
  }
}

// ---------------- K5: gamma LayerNorm (bf16 in, fp32 out), wave per row ----------------
__global__ __launch_bounds__(256) void k_ln(const bf16_t* __restrict__ out2b,
                                            const float* __restrict__ gamma,
                                            float* __restrict__ out) {
  const int lane = threadIdx.x & 63;
  const int row = blockIdx.x * 4 + (threadIdx.x >> 6);
  bf16x8 v = *(const bf16x8*)(out2b + (size_t)row * 512 + lane * 8);
  float f[8];
#pragma unroll
  for (int j = 0; j < 8; ++j) f[j] = (float)v[j];
  float s = 0.f, q = 0.f;
#pragma unroll
  for (int j = 0; j < 8; ++j) { s += f[j]; q += f[j] * f[j]; }
#pragma unroll
  for (int m = 1; m <= 32; m <<= 1) { s += __shfl_xor(s, m); q += __shfl_xor(q, m); }
  float mean = s * (1.f / 512.f);
  float var = q * (1.f / 512.f) - mean * mean;
  float rstd = rsqrtf(var + 1e-5f);
  float4 g0 = ((const float4*)gamma)[lane * 2];
  float4 g1 = ((const float4*)gamma)[lane * 2 + 1];
  float4 o0, o1;
  o0.x = (f[0] - mean) * rstd * g0.x;
  o0.y = (f[1] - mean) * rstd * g0.y;
  o0.z = (f[2] - mean) * rstd * g0.z;
  o0.w = (f[3] - mean) * rstd * g0.w;
  o1.x = (f[4] - mean) * rstd * g1.x;
  o1.y = (f[5] - mean) * rstd * g1.y;
  o1.z = (f[6] - mean) * rstd * g1.z;
  o1.w = (f[7] - mean) * rstd * g1.w;
  float* y = out + (size_t)row * 512;
  ((float4*)y)[lane * 2]     = o0;
  ((float4*)y)[lane * 2 + 1] = o1;
}

extern "C" void kernel_launch(void* const* d_in, const int* in_sizes, int n_in,
                              void* d_out, int out_size, void* d_ws, size_t ws_size,
                              hipStream_t stream) {
  const float* x     = (const float*)d_in[0];
  const float* w_qkv = (const float*)d_in[1];
  const float* w_out = (const float*)d_in[2];
  const float* gamma = (const float*)d_in[3];
  float* out = (float*)d_out;
  char* ws = (char*)d_ws;

  bf16_t* qs      = (bf16_t*)(ws);                       // 33,554,432
  bf16_t* ek      = (bf16_t*)(ws + 33554432);            // 33,554,432
  bf16_t* vb      = (bf16_t*)(ws + 67108864);            // 33,554,432
  bf16_t* wqkvb   = (bf16_t*)(ws + 100663296);           //  1,572,864
  float*  S       = (float*)(ws + 102236160);            //     16,384
  bf16_t* Xb      = (bf16_t*)(ws + 102252544);           // 33,554,432 (dead after k_qkv)
  float*  ctxpart = (float*)(ws + 103301120);            // alias Xb tail (written post-k_qkv)
  bf16_t* Mt      = (bf16_t*)(ws + 111689728);           // alias Xb tail
  bf16_t* out2b   = (bf16_t*)(ws + 33554432);            // alias ek (dead after k_ctx)

  hipMemsetAsync(S, 0, BATCH * 512 * sizeof(float), stream);

  k_cvt<<<384, 256, 0, stream>>>(w_qkv, wqkvb);
  k_cvt<<<8192, 256, 0, stream>>>(x, Xb);   // 16,777,216 elems / 2048 per block

  dim3 g1(128, 6);
  k_qkv<<<g1, 512, 0, stream>>>(Xb, wqkvb, qs, ek, vb, S);

  dim3 g2(64, 8);
  k_ctx<<<g2, 256, 0, stream>>>(ek, vb, ctxpart);

  k_mt<<<64, 256, 0, stream>>>(ctxpart, S, w_out, Mt);

  dim3 g5(128, 2);
  k_out<<<g5, 512, 0, stream>>>(qs, Mt, out2b);

  k_ln<<<8192, 256, 0, stream>>>(out2b, gamma, out);
}